// Round 12
// baseline (276.839 us; speedup 1.0000x reference)
//
#include <hip/hip_runtime.h>
#include <hip/hip_bf16.h>
#include <math.h>

typedef __attribute__((ext_vector_type(8))) short bf16x8;
typedef __attribute__((ext_vector_type(4))) float f32x4;

#define NB   2
#define CC   256
#define HH   80
#define WW   80
#define HWSZ 6400
#define MM   (NB * HWSZ)   // 12800
#define NCAT 768           // 256 (value) | 512 (om: g*32 + 27 used + 5 pad)
#define EPSB 1e-5f
#define NBLK 256

// ---------------------------------------------------------------------------
// Device-scope grid barrier (all 256 blocks co-resident: 96KB LDS -> 1/CU).
// Counters zeroed each launch via captured hipMemsetAsync.
// ---------------------------------------------------------------------------
__device__ __forceinline__ void gridbar(unsigned* cnt)
{
    __syncthreads();
    if (threadIdx.x == 0) {
        __threadfence();
        __hip_atomic_fetch_add(cnt, 1u, __ATOMIC_ACQ_REL, __HIP_MEMORY_SCOPE_AGENT);
        while (__hip_atomic_load(cnt, __ATOMIC_ACQUIRE, __HIP_MEMORY_SCOPE_AGENT) < (unsigned)NBLK) {}
        __threadfence();
    }
    __syncthreads();
}

// ---------------------------------------------------------------------------
// GEMM stage: 64x256 tile, BK=64, 8 waves (2m x 4n), K=256, 2-phase dbuf.
// EPI 0: +bias, bf16 row-major. EPI 1: BN+SiLU, bf16 row-major.
// ---------------------------------------------------------------------------
template <int EPI>
__device__ __forceinline__ void gemm64x256(
    const short* __restrict__ A, const short* __restrict__ Bt,
    const float* __restrict__ bias,
    const float* __restrict__ bng, const float* __restrict__ bnb,
    const float* __restrict__ bnm, const float* __restrict__ bnv,
    __hip_bfloat16* __restrict__ Cout, int ldC, int m0, int n0,
    char* smem, int t)
{
    short* As = (short*)smem;            // [2][64*64]   (16 KB)
    short* Bs = (short*)(smem + 16384);  // [2][256*64]  (64 KB)
    const int w = t >> 6, l = t & 63;
    const int wr = w >> 2, wc = w & 3;
    f32x4 acc[2][4] = {};

    auto STAGE = [&](int b, int k0) {
        short* AsB = As + b * 4096;
        short* BsB = Bs + b * 16384;
        {
            int row = t >> 3, ch = t & 7;
            const short* ga = A + (size_t)(m0 + row) * 256 + k0 + (ch << 3);
            __builtin_amdgcn_global_load_lds(
                (const __attribute__((address_space(1))) void*)ga,
                (__attribute__((address_space(3))) void*)(AsB + t * 8), 16, 0, 0);
        }
#pragma unroll
        for (int i = 0; i < 4; ++i) {
            int c = t + i * 512;
            int row = c >> 3, ch = c & 7;
            const short* gb = Bt + (size_t)(n0 + row) * 256 + k0 + (ch << 3);
            __builtin_amdgcn_global_load_lds(
                (const __attribute__((address_space(1))) void*)gb,
                (__attribute__((address_space(3))) void*)(BsB + c * 8), 16, 0, 0);
        }
    };

    STAGE(0, 0);
    __syncthreads();
#pragma unroll
    for (int tt = 0; tt < 4; ++tt) {
        if (tt < 3) STAGE((tt + 1) & 1, (tt + 1) * 64);
        const short* AsB = As + (tt & 1) * 4096;
        const short* BsB = Bs + (tt & 1) * 16384;
#pragma unroll
        for (int kk = 0; kk < 2; ++kk) {
            bf16x8 af[2], bfr[4];
#pragma unroll
            for (int mi = 0; mi < 2; ++mi)
                af[mi] = *(const bf16x8*)(AsB + (wr * 32 + mi * 16 + (l & 15)) * 64 +
                                          kk * 32 + ((l >> 4) << 3));
#pragma unroll
            for (int ni = 0; ni < 4; ++ni)
                bfr[ni] = *(const bf16x8*)(BsB + (wc * 64 + ni * 16 + (l & 15)) * 64 +
                                           kk * 32 + ((l >> 4) << 3));
#pragma unroll
            for (int mi = 0; mi < 2; ++mi)
#pragma unroll
                for (int ni = 0; ni < 4; ++ni)
                    acc[mi][ni] = __builtin_amdgcn_mfma_f32_16x16x32_bf16(
                        af[mi], bfr[ni], acc[mi][ni], 0, 0, 0);
        }
        __syncthreads();
    }

#pragma unroll
    for (int ni = 0; ni < 4; ++ni) {
        int chn = n0 + wc * 64 + ni * 16 + (l & 15);
        float bb = (EPI == 0) ? bias[chn] : 0.f;
        float mu = 0.f, iv = 0.f, gm = 0.f, bt2 = 0.f;
        if (EPI == 1) {
            mu = bnm[chn]; iv = rsqrtf(bnv[chn] + EPSB);
            gm = bng[chn]; bt2 = bnb[chn];
        }
#pragma unroll
        for (int mi = 0; mi < 2; ++mi) {
            int mbase = m0 + wr * 32 + mi * 16 + ((l >> 4) << 2);
#pragma unroll
            for (int j = 0; j < 4; ++j) {
                float v = acc[mi][ni][j] + bb;
                if (EPI == 1) {
                    v = (v - mu) * iv * gm + bt2;
                    v = v / (1.f + __expf(-v));
                }
                Cout[(size_t)(mbase + j) * ldC + chn] = __float2bfloat16(v);
            }
        }
    }
}

// ---------------------------------------------------------------------------
// P3: fused {deformable sampling -> LDS A} + GEMM3 + BN2/SiLU + NCHW out.
// ---------------------------------------------------------------------------
__device__ __forceinline__ void p3_fused(
    const __hip_bfloat16* __restrict__ C2, const short* __restrict__ woT,
    const float* __restrict__ bias,
    const float* __restrict__ bng, const float* __restrict__ bnb,
    const float* __restrict__ bnm, const float* __restrict__ bnv,
    float* __restrict__ out, int m0, char* smem, int t)
{
    short* As = (short*)smem;            // [64][256]  (32 KB)
    short* Bs = (short*)(smem + 32768);  // [2][256*64] (64 KB)
    const int w = t >> 6, l = t & 63;
    const int wr = w >> 2, wc = w & 3;
    const int nimg = m0 / HWSZ;
    const int p0 = m0 % HWSZ;

    auto STAGE_B = [&](int b, int k0) {
        short* BsB = Bs + b * 16384;
#pragma unroll
        for (int i = 0; i < 4; ++i) {
            int c = t + i * 512;
            int row = c >> 3, ch = c & 7;
            const short* gb = woT + (size_t)row * 256 + k0 + (ch << 3);
            __builtin_amdgcn_global_load_lds(
                (const __attribute__((address_space(1))) void*)gb,
                (__attribute__((address_space(3))) void*)(BsB + c * 8), 16, 0, 0);
        }
    };

    STAGE_B(0, 0);  // hide first B-tile HBM latency under sampler math

    // sampler: 1024 (px,g) tasks, 2/thread
#pragma unroll
    for (int it = 0; it < 2; ++it) {
        int task = it * 512 + t;
        int g = task & 15, px = task >> 4;
        int mp = m0 + px;
        int p = mp % HWSZ;
        int y = p / WW, x = p % WW;

        const unsigned* omw =
            (const unsigned*)(C2 + (size_t)mp * NCAT + 256 + g * 32);
        const __hip_bfloat16* vb = C2 + (size_t)nimg * HWSZ * NCAT + g * 16;

        float mk[9];
        {
            unsigned mw[5];
#pragma unroll
            for (int i = 0; i < 5; ++i) mw[i] = omw[9 + i];
#pragma unroll
            for (int i = 0; i < 9; ++i) {
                unsigned w16 = (i & 1) ? (mw[i >> 1] >> 16) : (mw[i >> 1] & 0xffffu);
                union { unsigned u; float f; } cv; cv.u = w16 << 16;
                mk[i] = cv.f;
            }
        }

        float acc[16] = {};
#pragma unroll
        for (int k = 0; k < 9; ++k) {
            unsigned ow = omw[k];
            union { unsigned u; float f; } cx, cy;
            cx.u = (ow & 0xffffu) << 16;
            cy.u = ow & 0xffff0000u;
            float px_ = (float)(x - 1 + (k % 3)) + cx.f;
            float py_ = (float)(y - 1 + (k / 3)) + cy.f;
            float fx = floorf(px_), fy = floorf(py_);
            float wx = px_ - fx, wy = py_ - fy;
            int x0 = (int)fx, y0 = (int)fy;
            int x1 = x0 + 1, y1 = y0 + 1;
            float ax0 = ((unsigned)x0 < (unsigned)WW) ? (1.f - wx) : 0.f;
            float ax1 = ((unsigned)x1 < (unsigned)WW) ? wx : 0.f;
            float ay0 = ((unsigned)y0 < (unsigned)HH) ? mk[k] * (1.f - wy) : 0.f;
            float ay1 = ((unsigned)y1 < (unsigned)HH) ? mk[k] * wy : 0.f;
            int xc0 = min(max(x0, 0), WW - 1);
            int xc1 = min(max(x1, 0), WW - 1);
            int yc0 = min(max(y0, 0), HH - 1);
            int yc1 = min(max(y1, 0), HH - 1);
            const __hip_bfloat16* r0 = vb + (size_t)(yc0 * WW) * NCAT;
            const __hip_bfloat16* r1 = vb + (size_t)(yc1 * WW) * NCAT;
            const __hip_bfloat16* pts[4] = {
                r0 + (size_t)xc0 * NCAT, r0 + (size_t)xc1 * NCAT,
                r1 + (size_t)xc0 * NCAT, r1 + (size_t)xc1 * NCAT };
            float wgt[4] = { ay0 * ax0, ay0 * ax1, ay1 * ax0, ay1 * ax1 };
#pragma unroll
            for (int q = 0; q < 4; ++q) {
                bf16x8 v0 = *(const bf16x8*)pts[q];
                bf16x8 v1 = *(const bf16x8*)(pts[q] + 8);
#pragma unroll
                for (int j = 0; j < 8; ++j) {
                    union { unsigned u; float f; } cv;
                    cv.u = ((unsigned)(unsigned short)v0[j]) << 16;
                    acc[j] = fmaf(wgt[q], cv.f, acc[j]);
                }
#pragma unroll
                for (int j = 0; j < 8; ++j) {
                    union { unsigned u; float f; } cv;
                    cv.u = ((unsigned)(unsigned short)v1[j]) << 16;
                    acc[8 + j] = fmaf(wgt[q], cv.f, acc[8 + j]);
                }
            }
        }

        bf16x8 ov0, ov1;
#pragma unroll
        for (int j = 0; j < 8; ++j) {
            __hip_bfloat16 b0 = __float2bfloat16(acc[j]);
            __hip_bfloat16 b1 = __float2bfloat16(acc[8 + j]);
            ov0[j] = *reinterpret_cast<short*>(&b0);
            ov1[j] = *reinterpret_cast<short*>(&b1);
        }
        *(bf16x8*)(As + px * 256 + g * 16) = ov0;
        *(bf16x8*)(As + px * 256 + g * 16 + 8) = ov1;
    }
    __syncthreads();

    // K-loop: A LDS-resident, B double-buffered
    f32x4 acc[2][4] = {};
#pragma unroll
    for (int tt = 0; tt < 4; ++tt) {
        if (tt < 3) STAGE_B((tt + 1) & 1, (tt + 1) * 64);
        const short* BsB = Bs + (tt & 1) * 16384;
        const int k0 = tt * 64;
#pragma unroll
        for (int kk = 0; kk < 2; ++kk) {
            bf16x8 af[2], bfr[4];
#pragma unroll
            for (int mi = 0; mi < 2; ++mi)
                af[mi] = *(const bf16x8*)(As + (wr * 32 + mi * 16 + (l & 15)) * 256 +
                                          k0 + kk * 32 + ((l >> 4) << 3));
#pragma unroll
            for (int ni = 0; ni < 4; ++ni)
                bfr[ni] = *(const bf16x8*)(BsB + (wc * 64 + ni * 16 + (l & 15)) * 64 +
                                           kk * 32 + ((l >> 4) << 3));
#pragma unroll
            for (int mi = 0; mi < 2; ++mi)
#pragma unroll
                for (int ni = 0; ni < 4; ++ni)
                    acc[mi][ni] = __builtin_amdgcn_mfma_f32_16x16x32_bf16(
                        af[mi], bfr[ni], acc[mi][ni], 0, 0, 0);
        }
        __syncthreads();
    }

    // epilogue: BN2 + SiLU + NCHW fp32 via LDS transpose
    float(*CtT)[68] = (float(*)[68])smem;
#pragma unroll
    for (int h2 = 0; h2 < 4; ++h2) {
        if (wc == h2) {
#pragma unroll
            for (int ni = 0; ni < 4; ++ni)
#pragma unroll
                for (int mi = 0; mi < 2; ++mi)
#pragma unroll
                    for (int j = 0; j < 4; ++j)
                        CtT[ni * 16 + (l & 15)]
                           [wr * 32 + mi * 16 + ((l >> 4) << 2) + j] =
                               acc[mi][ni][j];
        }
        __syncthreads();
#pragma unroll
        for (int it = 0; it < 2; ++it) {
            int e4 = it * 512 + t;
            int row = e4 >> 4;
            int c4 = e4 & 15;
            int chn = h2 * 64 + row;
            float bb = bias[chn];
            float mu = bnm[chn], iv = rsqrtf(bnv[chn] + EPSB);
            float gm = bng[chn], bt2 = bnb[chn];
            f32x4 v = *(f32x4*)&CtT[row][c4 * 4];
#pragma unroll
            for (int j = 0; j < 4; ++j) {
                float u = v[j] + bb;
                u = (u - mu) * iv * gm + bt2;
                u = u / (1.f + __expf(-u));
                v[j] = u;
            }
            *(f32x4*)&out[(size_t)(nimg * CC + chn) * HWSZ + p0 + c4 * 4] = v;
        }
        __syncthreads();
    }
}

// ---------------------------------------------------------------------------
// The persistent mega-kernel: P0 prep -> P1 gemm1 -> P2 gemm2 -> P3 fused.
// ---------------------------------------------------------------------------
__global__ __launch_bounds__(512) void mega_k(
    const float* __restrict__ x, const float* __restrict__ w1,
    const float* __restrict__ bn1g, const float* __restrict__ bn1b,
    const float* __restrict__ bn1m, const float* __restrict__ bn1v,
    const float* __restrict__ wv, const float* __restrict__ bv,
    const float* __restrict__ wom, const float* __restrict__ bom,
    const float* __restrict__ wo, const float* __restrict__ bo,
    const float* __restrict__ bn2g, const float* __restrict__ bn2b,
    const float* __restrict__ bn2m, const float* __restrict__ bn2v,
    __hip_bfloat16* __restrict__ xT, __hip_bfloat16* __restrict__ hbuf,
    __hip_bfloat16* __restrict__ C2, __hip_bfloat16* __restrict__ w1T,
    __hip_bfloat16* __restrict__ woT, __hip_bfloat16* __restrict__ BcatT,
    float* __restrict__ bcat, unsigned* __restrict__ bar,
    float* __restrict__ out)
{
    __shared__ __align__(16) char smem[98304];
    const int t = threadIdx.x;
    const int bid = blockIdx.x;

    // ---- P0: prep (3200 x-transpose tiles + 320 weight tiles + 1 bias) ----
    {
        float(*tiles)[32][33] = (float(*)[32][33])smem;
        const int half = t >> 8, tid = t & 255;
        const int tx = tid & 31, ty = tid >> 5;
        for (int it = 0; it < 7; ++it) {
            int task = it * 512 + bid * 2 + half;
            const float* gin = nullptr;
            __hip_bfloat16* gout = nullptr;
            int inld = 0, scol0 = 0, ncols = 0, orow0 = 0, r0 = 0;
            if (task < 3200) {
                int z = task / 1600, r = task % 1600;
                int by = r / 200, bx = r % 200;
                gin = x + (size_t)z * 256 * HWSZ; inld = HWSZ;
                scol0 = bx * 32; ncols = 32;
                gout = xT + (size_t)z * HWSZ * 256; orow0 = bx * 32; r0 = by * 32;
            } else if (task < 3264) {
                int b = task - 3200;
                gin = w1; inld = 256; scol0 = (b >> 3) * 32; ncols = 32;
                gout = w1T; orow0 = (b >> 3) * 32; r0 = (b & 7) * 32;
            } else if (task < 3328) {
                int b = task - 3264;
                gin = wv; inld = 256; scol0 = (b >> 3) * 32; ncols = 32;
                gout = BcatT; orow0 = (b >> 3) * 32; r0 = (b & 7) * 32;
            } else if (task < 3392) {
                int b = task - 3328;
                gin = wo; inld = 256; scol0 = (b >> 3) * 32; ncols = 32;
                gout = woT; orow0 = (b >> 3) * 32; r0 = (b & 7) * 32;
            } else if (task < 3520) {
                int b = task - 3392;
                int g = b >> 3, ct = b & 7;
                gin = wom; inld = 432; scol0 = g * 27; ncols = 27;
                gout = BcatT + 65536; orow0 = g * 32; r0 = ct * 32;
            } else if (task == 3520) {
                bcat[tid] = bv[tid];
#pragma unroll
                for (int j = 0; j < 2; ++j) {
                    int r = j * 256 + tid;
                    int g = r >> 5, jj = r & 31;
                    bcat[256 + r] = (jj < 27) ? bom[g * 27 + jj] : 0.f;
                }
            }
            if (gin) {
#pragma unroll
                for (int i = 0; i < 4; ++i) {
                    int row = ty + i * 8;
                    tiles[half][row][tx] = (tx < ncols)
                        ? gin[(size_t)(r0 + row) * inld + scol0 + tx] : 0.f;
                }
            }
            __syncthreads();
            if (gin) {
#pragma unroll
                for (int i = 0; i < 4; ++i) {
                    int row = ty + i * 8;
                    gout[(size_t)(orow0 + row) * 256 + r0 + tx] =
                        __float2bfloat16(tiles[half][tx][row]);
                }
            }
            __syncthreads();
        }
    }
    gridbar(bar + 0);

    // ---- P1: h = silu(bn1(xT @ w1T)), 200 tiles of 64x256 ----
    for (int task = bid; task < 200; task += NBLK)
        gemm64x256<1>((const short*)xT, (const short*)w1T, nullptr,
                      bn1g, bn1b, bn1m, bn1v, hbuf, 256, task * 64, 0, smem, t);
    gridbar(bar + 1);

    // ---- P2: C2 = hbuf @ BcatT + bcat, 600 tiles of 64x256 ----
    for (int task = bid; task < 600; task += NBLK)
        gemm64x256<0>((const short*)hbuf, (const short*)BcatT, bcat,
                      nullptr, nullptr, nullptr, nullptr, C2, NCAT,
                      (task % 200) * 64, (task / 200) * 256, smem, t);
    gridbar(bar + 2);

    // ---- P3: out = NCHW(silu(bn2(sample(C2) @ woT + bo))), 200 tiles ----
    for (int task = bid; task < 200; task += NBLK)
        p3_fused(C2, (const short*)woT, bo, bn2g, bn2b, bn2m, bn2v,
                 out, task * 64, smem, t);
}

// ---------------------------------------------------------------------------
extern "C" void kernel_launch(void* const* d_in, const int* in_sizes, int n_in,
                              void* d_out, int out_size, void* d_ws, size_t ws_size,
                              hipStream_t stream)
{
    const float* x    = (const float*)d_in[0];
    const float* w1   = (const float*)d_in[1];
    const float* bn1g = (const float*)d_in[2];
    const float* bn1b = (const float*)d_in[3];
    const float* bn1m = (const float*)d_in[4];
    const float* bn1v = (const float*)d_in[5];
    const float* wv   = (const float*)d_in[6];
    const float* bv   = (const float*)d_in[7];
    const float* wom  = (const float*)d_in[8];
    const float* bom  = (const float*)d_in[9];
    const float* wo   = (const float*)d_in[10];
    const float* bo   = (const float*)d_in[11];
    const float* bn2g = (const float*)d_in[12];
    const float* bn2b = (const float*)d_in[13];
    const float* bn2m = (const float*)d_in[14];
    const float* bn2v = (const float*)d_in[15];
    float* out = (float*)d_out;

    char* w = (char*)d_ws;
    __hip_bfloat16* xT    = (__hip_bfloat16*)(w);                 // [M][256]
    __hip_bfloat16* hbuf  = (__hip_bfloat16*)(w + 6553600);       // [M][256]
    __hip_bfloat16* C2    = (__hip_bfloat16*)(w + 13107200);      // [M][768]
    __hip_bfloat16* w1T   = (__hip_bfloat16*)(w + 39321600);      // [256][256]
    __hip_bfloat16* woT   = (__hip_bfloat16*)(w + 39452672);      // [256][256]
    __hip_bfloat16* BcatT = (__hip_bfloat16*)(w + 39583744);      // [768][256]
    float*          bcat  = (float*)(w + 39976960);               // [768]
    unsigned*       bar   = (unsigned*)(w + 41943040);            // barriers

    hipMemsetAsync(bar, 0, 64, stream);
    mega_k<<<dim3(NBLK), dim3(512), 0, stream>>>(
        x, w1, bn1g, bn1b, bn1m, bn1v, wv, bv, wom, bom, wo, bo,
        bn2g, bn2b, bn2m, bn2v,
        xT, hbuf, C2, w1T, woT, BcatT, bcat, bar, out);
}

// Round 13
// 150.383 us; speedup vs baseline: 1.8409x; 1.8409x over previous
//
#include <hip/hip_runtime.h>
#include <hip/hip_bf16.h>
#include <math.h>

typedef __attribute__((ext_vector_type(8))) short bf16x8;
typedef __attribute__((ext_vector_type(4))) float f32x4;

#define NB   2
#define CC   256
#define HH   80
#define WW   80
#define HWSZ 6400
#define MM   (NB * HWSZ)   // 12800
#define NCAT 768           // 256 (value) | 512 (om: g*32 + 27 used + 5 pad)
#define EPSB 1e-5f

// ---------------------------------------------------------------------------
// K1: merged prep — blocks 0..3199: x NCHW -> xT bf16; 3200..3520: weights
// ---------------------------------------------------------------------------
__device__ inline void t32g(const float* __restrict__ in, int inld, int scol0,
                            int ncols, __hip_bfloat16* __restrict__ out,
                            int orow0, int r0, int tid)
{
    __shared__ float tile[32][33];
    int tx = tid & 31, ty = tid >> 5;
#pragma unroll
    for (int i = 0; i < 32; i += 8)
        tile[ty + i][tx] = (tx < ncols)
            ? in[(size_t)(r0 + ty + i) * inld + scol0 + tx] : 0.f;
    __syncthreads();
#pragma unroll
    for (int i = 0; i < 32; i += 8)
        out[(size_t)(orow0 + ty + i) * 256 + r0 + tx] =
            __float2bfloat16(tile[tx][ty + i]);
}

__global__ __launch_bounds__(256) void prep_all_k(
    const float* __restrict__ x,
    const float* __restrict__ w1, const float* __restrict__ wv,
    const float* __restrict__ wom, const float* __restrict__ wo,
    const float* __restrict__ bv, const float* __restrict__ bom,
    __hip_bfloat16* __restrict__ xT,
    __hip_bfloat16* __restrict__ w1T, __hip_bfloat16* __restrict__ BcatT,
    __hip_bfloat16* __restrict__ woT, float* __restrict__ bcat)
{
    int b = blockIdx.x, t = threadIdx.x;
    if (b < 3200) {
        __shared__ float tile[32][33];
        int z = b / 1600, r = b % 1600;
        int by = r / 200, bx = r % 200;
        const float* inz = x + (size_t)256 * HWSZ * z;
        __hip_bfloat16* outz = xT + (size_t)HWSZ * 256 * z;
        int bc = bx * 32, br = by * 32;
        int tx = t & 31, ty = t >> 5;
#pragma unroll
        for (int i = 0; i < 32; i += 8)
            tile[ty + i][tx] = inz[(size_t)(br + ty + i) * HWSZ + bc + tx];
        __syncthreads();
#pragma unroll
        for (int i = 0; i < 32; i += 8)
            outz[(size_t)(bc + ty + i) * 256 + br + tx] =
                __float2bfloat16(tile[tx][ty + i]);
        return;
    }
    b -= 3200;
    if (b < 64) {
        t32g(w1, 256, (b >> 3) * 32, 32, w1T, (b >> 3) * 32, (b & 7) * 32, t);
    } else if (b < 128) {
        int b2 = b - 64;
        t32g(wv, 256, (b2 >> 3) * 32, 32, BcatT, (b2 >> 3) * 32, (b2 & 7) * 32, t);
    } else if (b < 192) {
        int b2 = b - 128;
        t32g(wo, 256, (b2 >> 3) * 32, 32, woT, (b2 >> 3) * 32, (b2 & 7) * 32, t);
    } else if (b < 320) {
        int b2 = b - 192;
        int g = b2 >> 3, ct = b2 & 7;
        t32g(wom, 432, g * 27, 27, BcatT + 256 * 256, g * 32, ct * 32, t);
    } else {
        bcat[t] = bv[t];
#pragma unroll
        for (int j = 0; j < 2; ++j) {
            int r = j * 256 + t;
            int g = r >> 5, jj = r & 31;
            bcat[256 + r] = (jj < 27) ? bom[g * 27 + jj] : 0.f;
        }
    }
}

// ---------------------------------------------------------------------------
// bf16 MFMA GEMM: 32x128 tile, BK=32 (8 K-steps), 4 waves (1m x 4n),
// 20KB LDS -> up to 8 blocks/CU. 2-phase double-buffered prefetch.
// EPI 0: +bias bf16; EPI 1: BN+SiLU bf16; EPI 2: bias+BN2+SiLU fp32 NCHW.
// ---------------------------------------------------------------------------
template <int EPI>
__global__ __launch_bounds__(256) void gemm_mfma(
    const short* __restrict__ A, const short* __restrict__ Bt,
    const float* __restrict__ bias,
    const float* __restrict__ bng, const float* __restrict__ bnb,
    const float* __restrict__ bnm, const float* __restrict__ bnv,
    void* __restrict__ Cout, int ldC)
{
    __shared__ __align__(16) char smem[20480];
    short* As = (short*)smem;            // [2][32*32]  (4 KB)
    short* Bs = (short*)(smem + 4096);   // [2][128*32] (16 KB)

    const int t = threadIdx.x;
    const int w = t >> 6, l = t & 63;
    const int wc = w;                    // 4 n-waves
    const int m0 = blockIdx.x * 32, n0 = blockIdx.y * 128;

    f32x4 acc[2][2] = {};

    auto STAGE = [&](int b, int k0) {
        short* AsB = As + b * 1024;
        short* BsB = Bs + b * 4096;
        if (t < 128) {                    // waves 0-1 stage A (128 x 16B)
            int row = t >> 2, ch = t & 3;
            const short* ga = A + (size_t)(m0 + row) * 256 + k0 + (ch << 3);
            __builtin_amdgcn_global_load_lds(
                (const __attribute__((address_space(1))) void*)ga,
                (__attribute__((address_space(3))) void*)(AsB + t * 8), 16, 0, 0);
        }
#pragma unroll
        for (int i = 0; i < 2; ++i) {     // all stage B (512 x 16B)
            int c = t + i * 256;
            int row = c >> 2, ch = c & 3;
            const short* gb = Bt + (size_t)(n0 + row) * 256 + k0 + (ch << 3);
            __builtin_amdgcn_global_load_lds(
                (const __attribute__((address_space(1))) void*)gb,
                (__attribute__((address_space(3))) void*)(BsB + c * 8), 16, 0, 0);
        }
    };

    STAGE(0, 0);
    __syncthreads();
#pragma unroll
    for (int tt = 0; tt < 8; ++tt) {
        if (tt < 7) STAGE((tt + 1) & 1, (tt + 1) * 32);
        const short* AsB = As + (tt & 1) * 1024;
        const short* BsB = Bs + (tt & 1) * 4096;
        bf16x8 af[2], bfr[2];
#pragma unroll
        for (int mi = 0; mi < 2; ++mi)
            af[mi] = *(const bf16x8*)(AsB + (mi * 16 + (l & 15)) * 32 +
                                      ((l >> 4) << 3));
#pragma unroll
        for (int ni = 0; ni < 2; ++ni)
            bfr[ni] = *(const bf16x8*)(BsB + (wc * 32 + ni * 16 + (l & 15)) * 32 +
                                       ((l >> 4) << 3));
#pragma unroll
        for (int mi = 0; mi < 2; ++mi)
#pragma unroll
            for (int ni = 0; ni < 2; ++ni)
                acc[mi][ni] = __builtin_amdgcn_mfma_f32_16x16x32_bf16(
                    af[mi], bfr[ni], acc[mi][ni], 0, 0, 0);
        __syncthreads();
    }

    if (EPI == 0 || EPI == 1) {
#pragma unroll
        for (int ni = 0; ni < 2; ++ni) {
            int chn = n0 + wc * 32 + ni * 16 + (l & 15);
            float bb = (EPI == 0) ? bias[chn] : 0.f;
            float mu = 0.f, iv = 0.f, gm = 0.f, bt2 = 0.f;
            if (EPI == 1) {
                mu = bnm[chn]; iv = rsqrtf(bnv[chn] + EPSB);
                gm = bng[chn]; bt2 = bnb[chn];
            }
#pragma unroll
            for (int mi = 0; mi < 2; ++mi) {
                int mbase = m0 + mi * 16 + ((l >> 4) << 2);
#pragma unroll
                for (int j = 0; j < 4; ++j) {
                    float v = acc[mi][ni][j] + bb;
                    if (EPI == 1) {
                        v = (v - mu) * iv * gm + bt2;
                        v = v / (1.f + __expf(-v));
                    }
                    ((__hip_bfloat16*)Cout)[(size_t)(mbase + j) * ldC + chn] =
                        __float2bfloat16(v);
                }
            }
        }
    } else {
        // EPI 2: LDS transpose [128 ch][32 m] -> NCHW fp32 with bias+BN2+SiLU
        float(*CtT)[36] = (float(*)[36])smem;   // 128*36*4 = 18432 B
        const int nimg = m0 / HWSZ;             // 6400 % 32 == 0
        const int p0 = m0 % HWSZ;
#pragma unroll
        for (int ni = 0; ni < 2; ++ni)
#pragma unroll
            for (int mi = 0; mi < 2; ++mi)
#pragma unroll
                for (int j = 0; j < 4; ++j)
                    CtT[wc * 32 + ni * 16 + (l & 15)]
                       [mi * 16 + ((l >> 4) << 2) + j] = acc[mi][ni][j];
        __syncthreads();
#pragma unroll
        for (int it = 0; it < 4; ++it) {
            int e4 = it * 256 + t;   // f32x4 idx over [128][8]
            int row = e4 >> 3;       // channel
            int c4 = e4 & 7;
            int chn = n0 + row;
            float bb = bias[chn];
            float mu = bnm[chn], iv = rsqrtf(bnv[chn] + EPSB);
            float gm = bng[chn], bt2 = bnb[chn];
            f32x4 v = *(f32x4*)&CtT[row][c4 * 4];
#pragma unroll
            for (int j = 0; j < 4; ++j) {
                float u = v[j] + bb;
                u = (u - mu) * iv * gm + bt2;
                u = u / (1.f + __expf(-u));
                v[j] = u;
            }
            *(f32x4*)&((float*)Cout)[(size_t)(nimg * CC + chn) * HWSZ + p0 + c4 * 4] = v;
        }
    }
}

// ---------------------------------------------------------------------------
// Deformable bilinear sampling: 16 channels/thread, bf16x8 gathers (round-9).
// ---------------------------------------------------------------------------
__device__ inline void fma16(float* acc, const __hip_bfloat16* ptr, float wgt)
{
    bf16x8 v0 = *(const bf16x8*)ptr;
    bf16x8 v1 = *(const bf16x8*)(ptr + 8);
#pragma unroll
    for (int j = 0; j < 8; ++j) {
        union { unsigned u; float f; } cv;
        cv.u = ((unsigned)(unsigned short)v0[j]) << 16;
        acc[j] = fmaf(wgt, cv.f, acc[j]);
    }
#pragma unroll
    for (int j = 0; j < 8; ++j) {
        union { unsigned u; float f; } cv;
        cv.u = ((unsigned)(unsigned short)v1[j]) << 16;
        acc[8 + j] = fmaf(wgt, cv.f, acc[8 + j]);
    }
}

__global__ __launch_bounds__(256) void dcn_sample_k(
    const __hip_bfloat16* __restrict__ C2, __hip_bfloat16* __restrict__ accb)
{
    const int idx = blockIdx.x * 256 + threadIdx.x;
    const int g = idx & 15;
    const int mp = idx >> 4;
    const int p = mp % HWSZ;
    const int n = mp / HWSZ;
    const int y = p / WW, x = p % WW;

    const unsigned* omw =
        (const unsigned*)(C2 + (size_t)mp * NCAT + 256 + g * 32);
    const __hip_bfloat16* vb =
        C2 + (size_t)n * HWSZ * NCAT + g * 16;

    float mk[9];
    {
        unsigned mw[5];
#pragma unroll
        for (int i = 0; i < 5; ++i) mw[i] = omw[9 + i];
#pragma unroll
        for (int i = 0; i < 9; ++i) {
            unsigned w16 = (i & 1) ? (mw[i >> 1] >> 16) : (mw[i >> 1] & 0xffffu);
            union { unsigned u; float f; } cv; cv.u = w16 << 16;
            mk[i] = cv.f;
        }
    }

    float acc[16] = {};
#pragma unroll
    for (int k = 0; k < 9; ++k) {
        unsigned ow = omw[k];
        union { unsigned u; float f; } cx, cy;
        cx.u = (ow & 0xffffu) << 16;
        cy.u = ow & 0xffff0000u;
        float px = (float)(x - 1 + (k % 3)) + cx.f;
        float py = (float)(y - 1 + (k / 3)) + cy.f;
        float fx = floorf(px), fy = floorf(py);
        float wx = px - fx, wy = py - fy;
        int x0 = (int)fx, y0 = (int)fy;
        int x1 = x0 + 1, y1 = y0 + 1;
        float ax0 = ((unsigned)x0 < (unsigned)WW) ? (1.f - wx) : 0.f;
        float ax1 = ((unsigned)x1 < (unsigned)WW) ? wx : 0.f;
        float ay0 = ((unsigned)y0 < (unsigned)HH) ? mk[k] * (1.f - wy) : 0.f;
        float ay1 = ((unsigned)y1 < (unsigned)HH) ? mk[k] * wy : 0.f;
        int xc0 = min(max(x0, 0), WW - 1);
        int xc1 = min(max(x1, 0), WW - 1);
        int yc0 = min(max(y0, 0), HH - 1);
        int yc1 = min(max(y1, 0), HH - 1);
        const __hip_bfloat16* r0 = vb + (size_t)(yc0 * WW) * NCAT;
        const __hip_bfloat16* r1 = vb + (size_t)(yc1 * WW) * NCAT;
        fma16(acc, r0 + (size_t)xc0 * NCAT, ay0 * ax0);
        fma16(acc, r0 + (size_t)xc1 * NCAT, ay0 * ax1);
        fma16(acc, r1 + (size_t)xc0 * NCAT, ay1 * ax0);
        fma16(acc, r1 + (size_t)xc1 * NCAT, ay1 * ax1);
    }

    __hip_bfloat16* op = accb + (size_t)mp * CC + g * 16;
    bf16x8 ov0, ov1;
#pragma unroll
    for (int j = 0; j < 8; ++j) {
        __hip_bfloat16 b0 = __float2bfloat16(acc[j]);
        __hip_bfloat16 b1 = __float2bfloat16(acc[8 + j]);
        ov0[j] = *reinterpret_cast<short*>(&b0);
        ov1[j] = *reinterpret_cast<short*>(&b1);
    }
    *(bf16x8*)op = ov0;
    *(bf16x8*)(op + 8) = ov1;
}

// ---------------------------------------------------------------------------
extern "C" void kernel_launch(void* const* d_in, const int* in_sizes, int n_in,
                              void* d_out, int out_size, void* d_ws, size_t ws_size,
                              hipStream_t stream)
{
    const float* x    = (const float*)d_in[0];
    const float* w1   = (const float*)d_in[1];
    const float* bn1g = (const float*)d_in[2];
    const float* bn1b = (const float*)d_in[3];
    const float* bn1m = (const float*)d_in[4];
    const float* bn1v = (const float*)d_in[5];
    const float* wv   = (const float*)d_in[6];
    const float* bv   = (const float*)d_in[7];
    const float* wom  = (const float*)d_in[8];
    const float* bom  = (const float*)d_in[9];
    const float* wo   = (const float*)d_in[10];
    const float* bo   = (const float*)d_in[11];
    const float* bn2g = (const float*)d_in[12];
    const float* bn2b = (const float*)d_in[13];
    const float* bn2m = (const float*)d_in[14];
    const float* bn2v = (const float*)d_in[15];
    float* out = (float*)d_out;

    char* w = (char*)d_ws;
    __hip_bfloat16* xT    = (__hip_bfloat16*)(w);                 // [M][256]
    __hip_bfloat16* hbuf  = (__hip_bfloat16*)(w + 6553600);       // [M][256]
    __hip_bfloat16* C2    = (__hip_bfloat16*)(w + 13107200);      // [M][768]
    __hip_bfloat16* accb  = (__hip_bfloat16*)(w + 32768000);      // [M][256]
    __hip_bfloat16* w1T   = (__hip_bfloat16*)(w + 39321600);      // [256][256]
    __hip_bfloat16* woT   = (__hip_bfloat16*)(w + 39452672);      // [256][256]
    __hip_bfloat16* BcatT = (__hip_bfloat16*)(w + 39583744);      // [768][256]
    float*          bcat  = (float*)(w + 39976960);               // [768]

    dim3 blk(256);

    // K1: all input/weight reformatting
    prep_all_k<<<dim3(3521), blk, 0, stream>>>(
        x, w1, wv, wom, wo, bv, bom, xT, w1T, BcatT, woT, bcat);

    // K2: h = silu(bn1(x @ w1))
    gemm_mfma<1><<<dim3(400, 2), blk, 0, stream>>>(
        (const short*)xT, (const short*)w1T, nullptr,
        bn1g, bn1b, bn1m, bn1v, hbuf, CC);

    // K3: C2 = h @ [wv|wom'] + bcat
    gemm_mfma<0><<<dim3(400, 6), blk, 0, stream>>>(
        (const short*)hbuf, (const short*)BcatT, bcat,
        nullptr, nullptr, nullptr, nullptr, C2, NCAT);

    // K4: deformable sampling -> accb
    dcn_sample_k<<<dim3(MM * 16 / 256), blk, 0, stream>>>(C2, accb);

    // K5: out = NCHW(silu(bn2(accb @ wo + bo)))
    gemm_mfma<2><<<dim3(400, 2), blk, 0, stream>>>(
        (const short*)accb, (const short*)woT, bo,
        bn2g, bn2b, bn2m, bn2v, out, 0);
}

// Round 14
// 148.384 us; speedup vs baseline: 1.8657x; 1.0135x over previous
//
#include <hip/hip_runtime.h>
#include <hip/hip_bf16.h>
#include <math.h>

typedef __attribute__((ext_vector_type(8))) short bf16x8;
typedef __attribute__((ext_vector_type(4))) float f32x4;

#define HH   80
#define WW   80
#define HWSZ 6400
#define MM   12800
#define NCAT 768           // 256 (value) | 512 (om: g*32 + 27 used + 5 pad)
#define EPSB 1e-5f
#define ALD  264           // padded LDS lda (shorts) for A tiles

#define AS1 __attribute__((address_space(1)))
#define AS3 __attribute__((address_space(3)))

// ---------------------------------------------------------------------------
// K1: weight prep only (x handled inside gemm12 now)
// ---------------------------------------------------------------------------
__device__ inline void t32g(const float* __restrict__ in, int inld, int scol0,
                            int ncols, __hip_bfloat16* __restrict__ out,
                            int orow0, int r0, int tid)
{
    __shared__ float tile[32][33];
    int tx = tid & 31, ty = tid >> 5;
#pragma unroll
    for (int i = 0; i < 32; i += 8)
        tile[ty + i][tx] = (tx < ncols)
            ? in[(size_t)(r0 + ty + i) * inld + scol0 + tx] : 0.f;
    __syncthreads();
#pragma unroll
    for (int i = 0; i < 32; i += 8)
        out[(size_t)(orow0 + ty + i) * 256 + r0 + tx] =
            __float2bfloat16(tile[tx][ty + i]);
}

__global__ __launch_bounds__(256) void prep_w_k(
    const float* __restrict__ w1, const float* __restrict__ wv,
    const float* __restrict__ wom, const float* __restrict__ wo,
    const float* __restrict__ bv, const float* __restrict__ bom,
    __hip_bfloat16* __restrict__ w1T, __hip_bfloat16* __restrict__ BcatT,
    __hip_bfloat16* __restrict__ woT, float* __restrict__ bcat)
{
    int b = blockIdx.x, t = threadIdx.x;
    if (b < 64) {
        t32g(w1, 256, (b >> 3) * 32, 32, w1T, (b >> 3) * 32, (b & 7) * 32, t);
    } else if (b < 128) {
        int b2 = b - 64;
        t32g(wv, 256, (b2 >> 3) * 32, 32, BcatT, (b2 >> 3) * 32, (b2 & 7) * 32, t);
    } else if (b < 192) {
        int b2 = b - 128;
        t32g(wo, 256, (b2 >> 3) * 32, 32, woT, (b2 >> 3) * 32, (b2 & 7) * 32, t);
    } else if (b < 320) {
        int b2 = b - 192;
        int g = b2 >> 3, ct = b2 & 7;
        t32g(wom, 432, g * 27, 27, BcatT + 256 * 256, g * 32, ct * 32, t);
    } else {
        bcat[t] = bv[t];
#pragma unroll
        for (int j = 0; j < 2; ++j) {
            int r = j * 256 + t;
            int g = r >> 5, jj = r & 31;
            bcat[256 + r] = (jj < 27) ? bom[g * 27 + jj] : 0.f;
        }
    }
}

// ---------------------------------------------------------------------------
// Swizzled B staging: [256 rows][32 k] of Bt(rows nb.., cols k0..) -> BsB.
// global_load_lds dest is forced linear, so swizzle the GLOBAL chunk index:
// lds chunk (row, cd) holds global chunk (row, cd ^ ((row>>1)&3)).  [T2/r21]
// ---------------------------------------------------------------------------
__device__ __forceinline__ void stageB(const short* __restrict__ Bt, int nb,
                                       int k0, short* BsB, int t)
{
#pragma unroll
    for (int i = 0; i < 4; ++i) {
        int c = t + i * 256;              // chunk 0..1023
        int row = c >> 2, cd = c & 3;
        int cs = cd ^ ((row >> 1) & 3);
        const short* gb = Bt + (size_t)(nb + row) * 256 + k0 + cs * 8;
        __builtin_amdgcn_global_load_lds((const AS1 void*)gb,
                                         (AS3 void*)(BsB + c * 8), 16, 0, 0);
    }
}

// matching read: B frag (n = wc*64+ni*16+(l&15), k-quarter l>>4)
__device__ __forceinline__ bf16x8 readB(const short* BsB, int wc, int ni, int l)
{
    int n = wc * 64 + ni * 16 + (l & 15);
    int cs = (l >> 4) ^ ((n >> 1) & 3);
    return *(const bf16x8*)(BsB + n * 32 + cs * 8);
}

// ---------------------------------------------------------------------------
// K2: fused  h = silu(bn1(x@w1)) ; C2 = h@[wv|wom'] + bcat.
// 400 blocks x 256 thr; M=32 strip; h LDS-resident; B streamed dbuf BK=32.
// LDS: Ax [32][264] bf16 (16.9KB) + Bs 2x[256][32] (32KB) = 48.5KB -> 3/CU.
// ---------------------------------------------------------------------------
__global__ __launch_bounds__(256) void gemm12_k(
    const float* __restrict__ x, const short* __restrict__ w1T,
    const short* __restrict__ BcatT, const float* __restrict__ bcat,
    const float* __restrict__ bn1g, const float* __restrict__ bn1b,
    const float* __restrict__ bn1m, const float* __restrict__ bn1v,
    __hip_bfloat16* __restrict__ C2)
{
    __shared__ __align__(16) char smem[49664];
    short* Ax = (short*)smem;             // [32][ALD]
    short* Bs = (short*)(smem + 16896);   // 2 x 8192 shorts

    const int t = threadIdx.x;
    const int l = t & 63, wc = t >> 6;    // 4 n-waves
    const int m0 = blockIdx.x * 32;
    const int nimg = m0 / HWSZ;
    const int p0 = m0 % HWSZ;

    // ---- stage x tile (NCHW, coalesced) -> Ax[m][c] bf16 ----
    {
        const int j0 = (t & 3) * 8;
#pragma unroll
        for (int cc = 0; cc < 4; ++cc) {
            int c = cc * 64 + (t >> 2);
            const float* src = x + (size_t)(nimg * 256 + c) * HWSZ + p0 + j0;
            f32x4 v0 = *(const f32x4*)src;
            f32x4 v1 = *(const f32x4*)(src + 4);
#pragma unroll
            for (int i = 0; i < 4; ++i)
                ((__hip_bfloat16*)Ax)[(j0 + i) * ALD + c] = __float2bfloat16(v0[i]);
#pragma unroll
            for (int i = 0; i < 4; ++i)
                ((__hip_bfloat16*)Ax)[(j0 + 4 + i) * ALD + c] = __float2bfloat16(v1[i]);
        }
    }
    stageB(w1T, 0, 0, Bs, t);
    __syncthreads();

    // ---- phase A: h = silu(bn1(x @ w1)) ----
    f32x4 acc[2][4] = {};
#pragma unroll
    for (int tt = 0; tt < 8; ++tt) {
        if (tt < 7) stageB(w1T, 0, (tt + 1) * 32, Bs + ((tt + 1) & 1) * 8192, t);
        const short* BsB = Bs + (tt & 1) * 8192;
        const int k0 = tt * 32;
        bf16x8 af[2], bfr[4];
#pragma unroll
        for (int mi = 0; mi < 2; ++mi)
            af[mi] = *(const bf16x8*)(Ax + (mi * 16 + (l & 15)) * ALD + k0 +
                                      ((l >> 4) << 3));
#pragma unroll
        for (int ni = 0; ni < 4; ++ni) bfr[ni] = readB(BsB, wc, ni, l);
#pragma unroll
        for (int mi = 0; mi < 2; ++mi)
#pragma unroll
            for (int ni = 0; ni < 4; ++ni)
                acc[mi][ni] = __builtin_amdgcn_mfma_f32_16x16x32_bf16(
                    af[mi], bfr[ni], acc[mi][ni], 0, 0, 0);
        __syncthreads();
    }

    // ---- bn1+silu -> h into Ax (overwrite; all x reads done) ----
#pragma unroll
    for (int ni = 0; ni < 4; ++ni) {
        int chn = wc * 64 + ni * 16 + (l & 15);
        float mu = bn1m[chn], iv = rsqrtf(bn1v[chn] + EPSB);
        float gm = bn1g[chn], bt2 = bn1b[chn];
#pragma unroll
        for (int mi = 0; mi < 2; ++mi) {
#pragma unroll
            for (int j = 0; j < 4; ++j) {
                int m = mi * 16 + ((l >> 4) << 2) + j;
                float v = acc[mi][ni][j];
                v = (v - mu) * iv * gm + bt2;
                v = v / (1.f + __expf(-v));
                ((__hip_bfloat16*)Ax)[m * ALD + chn] = __float2bfloat16(v);
            }
        }
    }
    __syncthreads();

    // ---- phase B: C2 = h @ BcatT + bcat, 3 n-chunks of 256 ----
    for (int nc = 0; nc < 3; ++nc) {
        f32x4 acc2[2][4] = {};
        stageB(BcatT, nc * 256, 0, Bs, t);
        __syncthreads();
#pragma unroll
        for (int tt = 0; tt < 8; ++tt) {
            if (tt < 7)
                stageB(BcatT, nc * 256, (tt + 1) * 32, Bs + ((tt + 1) & 1) * 8192, t);
            const short* BsB = Bs + (tt & 1) * 8192;
            const int k0 = tt * 32;
            bf16x8 af[2], bfr[4];
#pragma unroll
            for (int mi = 0; mi < 2; ++mi)
                af[mi] = *(const bf16x8*)(Ax + (mi * 16 + (l & 15)) * ALD + k0 +
                                          ((l >> 4) << 3));
#pragma unroll
            for (int ni = 0; ni < 4; ++ni) bfr[ni] = readB(BsB, wc, ni, l);
#pragma unroll
            for (int mi = 0; mi < 2; ++mi)
#pragma unroll
                for (int ni = 0; ni < 4; ++ni)
                    acc2[mi][ni] = __builtin_amdgcn_mfma_f32_16x16x32_bf16(
                        af[mi], bfr[ni], acc2[mi][ni], 0, 0, 0);
            __syncthreads();
        }
#pragma unroll
        for (int ni = 0; ni < 4; ++ni) {
            int chn = nc * 256 + wc * 64 + ni * 16 + (l & 15);
            float bb = bcat[chn];
#pragma unroll
            for (int mi = 0; mi < 2; ++mi) {
#pragma unroll
                for (int j = 0; j < 4; ++j) {
                    int m = m0 + mi * 16 + ((l >> 4) << 2) + j;
                    C2[(size_t)m * NCAT + chn] =
                        __float2bfloat16(acc2[mi][ni][j] + bb);
                }
            }
        }
    }
}

// ---------------------------------------------------------------------------
// K3: fused {deformable sampling -> LDS A} + gemm3 + BN2/SiLU + NCHW out.
// 400 blocks x 256 thr; M=32; LDS: Ax[32][264] + Bs 2x[256][32] = 48.5KB.
// ---------------------------------------------------------------------------
__global__ __launch_bounds__(256) void samp_gemm3_k(
    const __hip_bfloat16* __restrict__ C2, const short* __restrict__ woT,
    const float* __restrict__ bo,
    const float* __restrict__ bn2g, const float* __restrict__ bn2b,
    const float* __restrict__ bn2m, const float* __restrict__ bn2v,
    float* __restrict__ out)
{
    __shared__ __align__(16) char smem[49664];
    short* Ax = (short*)smem;             // [32][ALD] sampled A (bf16)
    short* Bs = (short*)(smem + 16896);   // 2 x 8192 shorts

    const int t = threadIdx.x;
    const int l = t & 63, wc = t >> 6;
    const int m0 = blockIdx.x * 32;
    const int nimg = m0 / HWSZ;
    const int p0 = m0 % HWSZ;

    stageB(woT, 0, 0, Bs, t);   // hide first B-tile under sampler math

    // ---- sampler: 512 (px,g) tasks, 2/thread ----
#pragma unroll
    for (int it = 0; it < 2; ++it) {
        int task = it * 256 + t;
        int g = task & 15, px = task >> 4;
        int mp = m0 + px;
        int p = mp % HWSZ;
        int y = p / WW, xx = p % WW;

        const unsigned* omw =
            (const unsigned*)(C2 + (size_t)mp * NCAT + 256 + g * 32);
        const __hip_bfloat16* vb = C2 + (size_t)nimg * HWSZ * NCAT + g * 16;

        float mk[9];
        {
            unsigned mw[5];
#pragma unroll
            for (int i = 0; i < 5; ++i) mw[i] = omw[9 + i];
#pragma unroll
            for (int i = 0; i < 9; ++i) {
                unsigned w16 = (i & 1) ? (mw[i >> 1] >> 16) : (mw[i >> 1] & 0xffffu);
                union { unsigned u; float f; } cv; cv.u = w16 << 16;
                mk[i] = cv.f;
            }
        }

        float acc[16] = {};
#pragma unroll
        for (int k = 0; k < 9; ++k) {
            unsigned ow = omw[k];
            union { unsigned u; float f; } cx, cy;
            cx.u = (ow & 0xffffu) << 16;
            cy.u = ow & 0xffff0000u;
            float px_ = (float)(xx - 1 + (k % 3)) + cx.f;
            float py_ = (float)(y - 1 + (k / 3)) + cy.f;
            float fx = floorf(px_), fy = floorf(py_);
            float wx = px_ - fx, wy = py_ - fy;
            int x0 = (int)fx, y0 = (int)fy;
            int x1 = x0 + 1, y1 = y0 + 1;
            float ax0 = ((unsigned)x0 < (unsigned)WW) ? (1.f - wx) : 0.f;
            float ax1 = ((unsigned)x1 < (unsigned)WW) ? wx : 0.f;
            float ay0 = ((unsigned)y0 < (unsigned)HH) ? mk[k] * (1.f - wy) : 0.f;
            float ay1 = ((unsigned)y1 < (unsigned)HH) ? mk[k] * wy : 0.f;
            int xc0 = min(max(x0, 0), WW - 1);
            int xc1 = min(max(x1, 0), WW - 1);
            int yc0 = min(max(y0, 0), HH - 1);
            int yc1 = min(max(y1, 0), HH - 1);
            const __hip_bfloat16* r0 = vb + (size_t)(yc0 * WW) * NCAT;
            const __hip_bfloat16* r1 = vb + (size_t)(yc1 * WW) * NCAT;
            const __hip_bfloat16* pts[4] = {
                r0 + (size_t)xc0 * NCAT, r0 + (size_t)xc1 * NCAT,
                r1 + (size_t)xc0 * NCAT, r1 + (size_t)xc1 * NCAT };
            float wgt[4] = { ay0 * ax0, ay0 * ax1, ay1 * ax0, ay1 * ax1 };
#pragma unroll
            for (int q = 0; q < 4; ++q) {
                bf16x8 v0 = *(const bf16x8*)pts[q];
                bf16x8 v1 = *(const bf16x8*)(pts[q] + 8);
#pragma unroll
                for (int j = 0; j < 8; ++j) {
                    union { unsigned u; float f; } cv;
                    cv.u = ((unsigned)(unsigned short)v0[j]) << 16;
                    acc[j] = fmaf(wgt[q], cv.f, acc[j]);
                }
#pragma unroll
                for (int j = 0; j < 8; ++j) {
                    union { unsigned u; float f; } cv;
                    cv.u = ((unsigned)(unsigned short)v1[j]) << 16;
                    acc[8 + j] = fmaf(wgt[q], cv.f, acc[8 + j]);
                }
            }
        }

        bf16x8 ov0, ov1;
#pragma unroll
        for (int j = 0; j < 8; ++j) {
            __hip_bfloat16 b0 = __float2bfloat16(acc[j]);
            __hip_bfloat16 b1 = __float2bfloat16(acc[8 + j]);
            ov0[j] = *reinterpret_cast<short*>(&b0);
            ov1[j] = *reinterpret_cast<short*>(&b1);
        }
        *(bf16x8*)(Ax + px * ALD + g * 16) = ov0;
        *(bf16x8*)(Ax + px * ALD + g * 16 + 8) = ov1;
    }
    __syncthreads();

    // ---- K-loop: A LDS-resident, B dbuf, BK=32 x 8 ----
    f32x4 acc[2][4] = {};
#pragma unroll
    for (int tt = 0; tt < 8; ++tt) {
        if (tt < 7) stageB(woT, 0, (tt + 1) * 32, Bs + ((tt + 1) & 1) * 8192, t);
        const short* BsB = Bs + (tt & 1) * 8192;
        const int k0 = tt * 32;
        bf16x8 af[2], bfr[4];
#pragma unroll
        for (int mi = 0; mi < 2; ++mi)
            af[mi] = *(const bf16x8*)(Ax + (mi * 16 + (l & 15)) * ALD + k0 +
                                      ((l >> 4) << 3));
#pragma unroll
        for (int ni = 0; ni < 4; ++ni) bfr[ni] = readB(BsB, wc, ni, l);
#pragma unroll
        for (int mi = 0; mi < 2; ++mi)
#pragma unroll
            for (int ni = 0; ni < 4; ++ni)
                acc[mi][ni] = __builtin_amdgcn_mfma_f32_16x16x32_bf16(
                    af[mi], bfr[ni], acc[mi][ni], 0, 0, 0);
        __syncthreads();
    }

    // ---- epilogue: bias + BN2 + SiLU + NCHW fp32 via LDS transpose ----
    float(*CtT)[36] = (float(*)[36])smem;   // [256 ch][32 m] +pad = 36.9KB
#pragma unroll
    for (int ni = 0; ni < 4; ++ni)
#pragma unroll
        for (int mi = 0; mi < 2; ++mi)
#pragma unroll
            for (int j = 0; j < 4; ++j)
                CtT[wc * 64 + ni * 16 + (l & 15)]
                   [mi * 16 + ((l >> 4) << 2) + j] = acc[mi][ni][j];
    __syncthreads();
#pragma unroll
    for (int i = 0; i < 8; ++i) {
        int e4 = i * 256 + t;   // f32x4 index over [256][8]
        int chn = e4 >> 3;
        int c4 = e4 & 7;
        float bb = bo[chn];
        float mu = bn2m[chn], iv = rsqrtf(bn2v[chn] + EPSB);
        float gm = bn2g[chn], bt2 = bn2b[chn];
        f32x4 v = *(f32x4*)&CtT[chn][c4 * 4];
#pragma unroll
        for (int j = 0; j < 4; ++j) {
            float u = v[j] + bb;
            u = (u - mu) * iv * gm + bt2;
            u = u / (1.f + __expf(-u));
            v[j] = u;
        }
        *(f32x4*)&out[(size_t)(nimg * 256 + chn) * HWSZ + p0 + c4 * 4] = v;
    }
}

// ---------------------------------------------------------------------------
extern "C" void kernel_launch(void* const* d_in, const int* in_sizes, int n_in,
                              void* d_out, int out_size, void* d_ws, size_t ws_size,
                              hipStream_t stream)
{
    const float* x    = (const float*)d_in[0];
    const float* w1   = (const float*)d_in[1];
    const float* bn1g = (const float*)d_in[2];
    const float* bn1b = (const float*)d_in[3];
    const float* bn1m = (const float*)d_in[4];
    const float* bn1v = (const float*)d_in[5];
    const float* wv   = (const float*)d_in[6];
    const float* bv   = (const float*)d_in[7];
    const float* wom  = (const float*)d_in[8];
    const float* bom  = (const float*)d_in[9];
    const float* wo   = (const float*)d_in[10];
    const float* bo   = (const float*)d_in[11];
    const float* bn2g = (const float*)d_in[12];
    const float* bn2b = (const float*)d_in[13];
    const float* bn2m = (const float*)d_in[14];
    const float* bn2v = (const float*)d_in[15];
    float* out = (float*)d_out;

    char* w = (char*)d_ws;
    __hip_bfloat16* C2    = (__hip_bfloat16*)(w);                 // [M][768]
    __hip_bfloat16* w1T   = (__hip_bfloat16*)(w + 19660800);      // [256][256]
    __hip_bfloat16* woT   = (__hip_bfloat16*)(w + 19791872);      // [256][256]
    __hip_bfloat16* BcatT = (__hip_bfloat16*)(w + 19922944);      // [768][256]
    float*          bcat  = (float*)(w + 20316160);               // [768]

    dim3 blk(256);

    // K1: weight reformatting
    prep_w_k<<<dim3(321), blk, 0, stream>>>(
        w1, wv, wom, wo, bv, bom, w1T, BcatT, woT, bcat);

    // K2: C2 = silu(bn1(x@w1)) @ [wv|wom'] + bcat   (h LDS-resident)
    gemm12_k<<<dim3(400), blk, 0, stream>>>(
        x, (const short*)w1T, (const short*)BcatT, bcat,
        bn1g, bn1b, bn1m, bn1v, C2);

    // K3: out = NCHW(silu(bn2(sample(C2) @ wo + bo)))
    samp_gemm3_k<<<dim3(400), blk, 0, stream>>>(
        C2, (const short*)woT, bo, bn2g, bn2b, bn2m, bn2v, out);
}